// Round 2
// baseline (7666.222 us; speedup 1.0000x reference)
//
#include <hip/hip_runtime.h>

__device__ __forceinline__ float sigmoidf_(float x) {
    return 1.0f / (1.0f + __expf(-x));
}

// C[M,N] = A[M,K] @ B[N,K]^T + bias[N], optional tanh epilogue.
// 64x64 tile, BK=32, 256 threads, 4x4 micro-tile. M,N multiples of 64, K of 32.
template<bool TANH>
__global__ __launch_bounds__(256) void gemm_nt_bias(
    const float* __restrict__ A, const float* __restrict__ B,
    const float* __restrict__ bias, float* __restrict__ C,
    const int N, const int K)
{
    __shared__ float As[32][68];   // [k][m], pad 4 -> 16B-aligned rows
    __shared__ float Bs[32][68];   // [k][n]
    const int nb = blockIdx.x, mb = blockIdx.y;
    const int t  = threadIdx.x;
    const int tx = t & 15, ty = t >> 4;
    const int lr = t >> 3;          // 0..31 (staging row)
    const int lk = (t & 7) << 2;    // 0..28 (staging k quad)
    const float* pA = A + (size_t)(mb * 64 + lr) * K + lk;
    const float* pB = B + (size_t)(nb * 64 + lr) * K + lk;

    float acc[4][4];
#pragma unroll
    for (int i = 0; i < 4; ++i)
#pragma unroll
        for (int j = 0; j < 4; ++j) acc[i][j] = 0.0f;

    for (int kk = 0; kk < K; kk += 32) {
        const float4 a0 = *(const float4*)(pA + kk);
        const float4 a1 = *(const float4*)(pA + (size_t)32 * K + kk);
        const float4 b0 = *(const float4*)(pB + kk);
        const float4 b1 = *(const float4*)(pB + (size_t)32 * K + kk);
        __syncthreads();
        As[lk+0][lr] = a0.x; As[lk+1][lr] = a0.y; As[lk+2][lr] = a0.z; As[lk+3][lr] = a0.w;
        As[lk+0][lr+32] = a1.x; As[lk+1][lr+32] = a1.y; As[lk+2][lr+32] = a1.z; As[lk+3][lr+32] = a1.w;
        Bs[lk+0][lr] = b0.x; Bs[lk+1][lr] = b0.y; Bs[lk+2][lr] = b0.z; Bs[lk+3][lr] = b0.w;
        Bs[lk+0][lr+32] = b1.x; Bs[lk+1][lr+32] = b1.y; Bs[lk+2][lr+32] = b1.z; Bs[lk+3][lr+32] = b1.w;
        __syncthreads();
#pragma unroll
        for (int k = 0; k < 32; ++k) {
            const float4 av = *(const float4*)&As[k][ty << 2];
            const float4 bv = *(const float4*)&Bs[k][tx << 2];
            acc[0][0] += av.x * bv.x; acc[0][1] += av.x * bv.y; acc[0][2] += av.x * bv.z; acc[0][3] += av.x * bv.w;
            acc[1][0] += av.y * bv.x; acc[1][1] += av.y * bv.y; acc[1][2] += av.y * bv.z; acc[1][3] += av.y * bv.w;
            acc[2][0] += av.z * bv.x; acc[2][1] += av.z * bv.y; acc[2][2] += av.z * bv.z; acc[2][3] += av.z * bv.w;
            acc[3][0] += av.w * bv.x; acc[3][1] += av.w * bv.y; acc[3][2] += av.w * bv.z; acc[3][3] += av.w * bv.w;
        }
    }
    const int crow = mb * 64 + (ty << 2);
    const int ccol = nb * 64 + (tx << 2);
    const float4 bv = *(const float4*)(bias + ccol);
#pragma unroll
    for (int i = 0; i < 4; ++i) {
        float4 o;
        o.x = acc[i][0] + bv.x; o.y = acc[i][1] + bv.y;
        o.z = acc[i][2] + bv.z; o.w = acc[i][3] + bv.w;
        if (TANH) { o.x = tanhf(o.x); o.y = tanhf(o.y); o.z = tanhf(o.z); o.w = tanhf(o.w); }
        *(float4*)(C + (size_t)(crow + i) * N + ccol) = o;
    }
}

// One GRU timestep. Grid = 256 WGs (16 row-tiles x 16 col-tiles), 256 threads.
// Per thread: 2 batch rows {rp, rp+8} x 3 gates for one h-col.
// LDS pads chosen so all inner-loop b128 reads are bank-conflict-free:
//   Hs stride 516 floats (129 quads, odd mod 8), Ws stride 68 (17 quads).
// No grid-wide sync needed: h(t) -> h(t+1) dependency is enforced by the
// kernel launch boundary (same stream).
__global__ __launch_bounds__(256) void gru_step(
    const float* __restrict__ gi_s,  // [256,1536] precomputed x_t@w_ih^T + b_ih
    const float* __restrict__ whh,   // [1536,512]
    const float* __restrict__ bhh,   // [1536]
    const float* __restrict__ hc,    // [256,512] h(t-1)
    float* __restrict__ hn)          // [256,512] h(t)
{
    __shared__ float Hs[16][516];   // h rows of this row-tile, full K=512
    __shared__ float Ws[96][68];    // 3 gates x 32 cols, K-chunk of 64
    const int bid = blockIdx.x;
    const int rm = bid >> 4;        // row tile (16 rows)
    const int cn = bid & 15;        // col tile (32 h-cols)
    const int t  = threadIdx.x;
    const int c  = t >> 3;          // 0..31 local h-col (8 lanes share c -> LDS bcast)
    const int rp = t & 7;           // rows rp, rp+8
    const int col = (cn << 5) + c;
    const float bhr = bhh[col], bhz = bhh[512 + col], bhn = bhh[1024 + col];
    const int sr = t >> 4;          // staging row 0..15
    const int sq = (t & 15) << 2;   // staging quad offset

    // stage Hs: 16 rows x 512 (visible after first __syncthreads below)
    {
        const float* src = hc + (size_t)((rm << 4) + sr) * 512 + sq;
        float* dst = &Hs[sr][sq];
#pragma unroll
        for (int ss = 0; ss < 8; ++ss)
            *(float4*)(dst + (ss << 6)) = *(const float4*)(src + (ss << 6));
    }
    float a00 = 0.f, a01 = 0.f, a02 = 0.f, a10 = 0.f, a11 = 0.f, a12 = 0.f;
    for (int kk = 0; kk < 512; kk += 64) {
        __syncthreads();               // prev-chunk Ws readers done; Hs writes visible
#pragma unroll
        for (int ss = 0; ss < 6; ++ss) {  // stage Ws: 96 rows x 64
            const int r2 = sr + (ss << 4);
            const int g = r2 >> 5, cc = r2 & 31;
            *(float4*)&Ws[r2][sq] =
                *(const float4*)(whh + (size_t)((g << 9) + (cn << 5) + cc) * 512 + kk + sq);
        }
        __syncthreads();
#pragma unroll
        for (int k = 0; k < 64; k += 4) {
            const float4 h0 = *(const float4*)&Hs[rp][kk + k];
            const float4 h1 = *(const float4*)&Hs[rp + 8][kk + k];
            const float4 w0 = *(const float4*)&Ws[c][k];
            const float4 w1 = *(const float4*)&Ws[32 + c][k];
            const float4 w2 = *(const float4*)&Ws[64 + c][k];
            a00 += h0.x*w0.x + h0.y*w0.y + h0.z*w0.z + h0.w*w0.w;
            a01 += h0.x*w1.x + h0.y*w1.y + h0.z*w1.z + h0.w*w1.w;
            a02 += h0.x*w2.x + h0.y*w2.y + h0.z*w2.z + h0.w*w2.w;
            a10 += h1.x*w0.x + h1.y*w0.y + h1.z*w0.z + h1.w*w0.w;
            a11 += h1.x*w1.x + h1.y*w1.y + h1.z*w1.z + h1.w*w1.w;
            a12 += h1.x*w2.x + h1.y*w2.y + h1.z*w2.z + h1.w*w2.w;
        }
    }
    // epilogue: gates + state update for rows rg0, rg1
    const int rg0 = (rm << 4) + rp;
    const int rg1 = rg0 + 8;
    const float* gp0 = gi_s + (size_t)rg0 * 1536 + col;
    const float* gp1 = gi_s + (size_t)rg1 * 1536 + col;
    const float r0 = sigmoidf_(gp0[0]   + a00 + bhr);
    const float z0 = sigmoidf_(gp0[512] + a01 + bhz);
    const float n0 = tanhf(gp0[1024] + r0 * (a02 + bhn));
    const float hv0 = (1.0f - z0) * n0 + z0 * Hs[rp][col];
    const float r1 = sigmoidf_(gp1[0]   + a10 + bhr);
    const float z1 = sigmoidf_(gp1[512] + a11 + bhz);
    const float n1 = tanhf(gp1[1024] + r1 * (a12 + bhn));
    const float hv1 = (1.0f - z1) * n1 + z1 * Hs[rp + 8][col];
    hn[(size_t)rg0 * 512 + col] = hv0;
    hn[(size_t)rg1 * 512 + col] = hv1;
}

// value[b] = tanh(dot(out1[b,:512], W2[:512]) + b2)
__global__ __launch_bounds__(256) void value_head(
    const float* __restrict__ out1, const float* __restrict__ W2,
    const float* __restrict__ b2, float* __restrict__ out)
{
    const int b = blockIdx.x, t = threadIdx.x;
    float p = out1[(size_t)b * 512 + t] * W2[t]
            + out1[(size_t)b * 512 + 256 + t] * W2[256 + t];
#pragma unroll
    for (int off = 32; off > 0; off >>= 1) p += __shfl_down(p, off, 64);
    __shared__ float ps[4];
    if ((t & 63) == 0) ps[t >> 6] = p;
    __syncthreads();
    if (t == 0) out[b] = tanhf(ps[0] + ps[1] + ps[2] + ps[3] + b2[0]);
}

extern "C" void kernel_launch(void* const* d_in, const int* in_sizes, int n_in,
                              void* d_out, int out_size, void* d_ws, size_t ws_size,
                              hipStream_t stream)
{
    (void)in_sizes; (void)n_in; (void)out_size;
    const float* input = (const float*)d_in[0];   // [256,256,512]
    const float* w_ih  = (const float*)d_in[1];   // [1536,512]
    const float* w_hh  = (const float*)d_in[2];   // [1536,512]
    const float* b_ih  = (const float*)d_in[3];   // [1536]
    const float* b_hh  = (const float*)d_in[4];   // [1536]
    const float* W1    = (const float*)d_in[5];   // [512,512]
    const float* b1    = (const float*)d_in[6];   // [512]
    const float* W2    = (const float*)d_in[7];   // [512]
    const float* b2    = (const float*)d_in[8];   // [1]
    float* out = (float*)d_out;
    float* ws  = (float*)d_ws;

    // ws layout (floats): h ping-pong 2x131072, out1 131072, then gi chunk
    float* h0 = ws;
    float* h1 = ws + 131072;
    float* o1 = ws + 262144;
    float* gi = ws + 393216;

    const size_t per_step = 256 * 1536;           // gi floats per timestep
    const size_t avail = (ws_size / 4 > 393216) ? ws_size / 4 - 393216 : 0;
    int Tc = (int)(avail / per_step);
    if (Tc > 256) Tc = 256;
    if (Tc < 1) Tc = 1;

    hipMemsetAsync(h0, 0, 131072 * sizeof(float), stream);  // h(-1) = 0

    float* hcur = h0;
    float* hnxt = h1;
    for (int t0 = 0; t0 < 256; t0 += Tc) {
        const int tc = (t0 + Tc <= 256) ? Tc : (256 - t0);
        const int Mc = tc * 256;
        // Phase 1 (chunk): gi = X_chunk @ w_ih^T + b_ih
        gemm_nt_bias<false><<<dim3(1536 / 64, Mc / 64), 256, 0, stream>>>(
            input + (size_t)t0 * 256 * 512, w_ih, b_ih, gi, 1536, 512);
        // Phase 2 (chunk): one kernel per timestep; launch boundary = grid barrier
        for (int s = 0; s < tc; ++s) {
            gru_step<<<dim3(256), dim3(256), 0, stream>>>(
                gi + (size_t)s * per_step, w_hh, b_hh, hcur, hnxt);
            float* tmp = hcur; hcur = hnxt; hnxt = tmp;
        }
    }

    // Phase 3: value head on final h (in hcur after 256 swaps -> h0)
    gemm_nt_bias<true><<<dim3(512 / 64, 256 / 64), 256, 0, stream>>>(
        hcur, W1, b1, o1, 512, 512);
    value_head<<<256, 256, 0, stream>>>(o1, W2, b2, out);
}

// Round 5
// 5834.990 us; speedup vs baseline: 1.3138x; 1.3138x over previous
//
#include <hip/hip_runtime.h>
#include <hip/hip_bf16.h>

typedef __attribute__((ext_vector_type(8))) short short8v;   // 8 bf16 = 16 B
typedef __attribute__((ext_vector_type(4))) float f32x4;

union SV { short8v v; unsigned short u[8]; };
union FU { float f; unsigned u; };

// Truncation split: x ~= hi + lo, residual <= 2^-16 |x|. 3 VALU ops.
__device__ __forceinline__ void split2(float x, unsigned short& hi, unsigned short& lo) {
    FU a; a.f = x;
    hi = (unsigned short)(a.u >> 16);
    FU h; h.u = a.u & 0xffff0000u;
    FU r; r.f = x - h.f;              // exact
    lo = (unsigned short)(r.u >> 16);
}
__device__ __forceinline__ void split8(const float4 a0, const float4 a1, SV& h, SV& l) {
    split2(a0.x, h.u[0], l.u[0]); split2(a0.y, h.u[1], l.u[1]);
    split2(a0.z, h.u[2], l.u[2]); split2(a0.w, h.u[3], l.u[3]);
    split2(a1.x, h.u[4], l.u[4]); split2(a1.y, h.u[5], l.u[5]);
    split2(a1.z, h.u[6], l.u[6]); split2(a1.w, h.u[7], l.u[7]);
}
__device__ __forceinline__ float sigmoidf_(float x) {
    return 1.0f / (1.0f + __expf(-x));
}

// ---- Phase 1: gi = X @ w_ih^T + b_ih. Split-bf16 MFMA (3 products). ----
// 128x128 tile, BK=64, 256 thr (4 waves, 2x2 quadrants of 64x64).
// Both operands split in-register from fp32 while staging (no bf16 copies
// exist anywhere in ws -> no layout-overlap failure class).
// Linear LDS writes with pre-swizzled k-slot; XOR-swizzled b128 reads.
__global__ __launch_bounds__(256, 2) void gemm_gi_mfma(
    const float* __restrict__ A,      // [M,512] fp32
    const float* __restrict__ B,      // [1536,512] fp32 (w_ih)
    const float* __restrict__ bias,   // [1536]
    float* __restrict__ C)            // [M,1536]
{
    __shared__ __attribute__((aligned(16))) unsigned char lds[65536];
    // A_hi[0,16K) A_lo[16K,32K) B_hi[32K,48K) B_lo[48K,64K)
    const int t = threadIdx.x;
    const int l = t & 63, w = t >> 6;
    const int nb = blockIdx.x, mb = blockIdx.y;
    const int p = t & 7;            // 16B slot within 64-K row
    const int rbase = t >> 3;       // 0..31
    f32x4 acc[4][4] = {};

    for (int kk = 0; kk < 512; kk += 64) {
#pragma unroll
        for (int i = 0; i < 4; ++i) {
            const int r = i * 32 + rbase;            // tile row 0..127
            const int q = p ^ (r & 7);               // pre-swizzled k-slot
            const float* ga = A + (size_t)(mb * 128 + r) * 512 + kk + q * 8;
            const float* gb = B + (size_t)(nb * 128 + r) * 512 + kk + q * 8;
            SV ah, al, bh, bl;
            split8(*(const float4*)ga, *(const float4*)(ga + 4), ah, al);
            split8(*(const float4*)gb, *(const float4*)(gb + 4), bh, bl);
            const int o = r * 128 + p * 16;
            *(short8v*)&lds[o] = ah.v;
            *(short8v*)&lds[16384 + o] = al.v;
            *(short8v*)&lds[32768 + o] = bh.v;
            *(short8v*)&lds[49152 + o] = bl.v;
        }
        __syncthreads();
        const int mr0 = (w >> 1) * 64, nc0 = (w & 1) * 64;
#pragma unroll
        for (int kk2 = 0; kk2 < 2; ++kk2) {
            const int kap = kk2 * 4 + (l >> 4);      // logical k-slot 0..7
            short8v ah[4], al[4], bh[4], bl[4];
#pragma unroll
            for (int i = 0; i < 4; ++i) {
                const int row = mr0 + i * 16 + (l & 15);
                const int off = row * 128 + ((kap ^ (row & 7)) * 16);
                ah[i] = *(const short8v*)&lds[off];
                al[i] = *(const short8v*)&lds[16384 + off];
            }
#pragma unroll
            for (int j = 0; j < 4; ++j) {
                const int bn = nc0 + j * 16 + (l & 15);
                const int off = bn * 128 + ((kap ^ (bn & 7)) * 16);
                bh[j] = *(const short8v*)&lds[32768 + off];
                bl[j] = *(const short8v*)&lds[49152 + off];
            }
#pragma unroll
            for (int i = 0; i < 4; ++i)
#pragma unroll
                for (int j = 0; j < 4; ++j) {
                    acc[i][j] = __builtin_amdgcn_mfma_f32_16x16x32_bf16(ah[i], bh[j], acc[i][j], 0, 0, 0);
                    acc[i][j] = __builtin_amdgcn_mfma_f32_16x16x32_bf16(ah[i], bl[j], acc[i][j], 0, 0, 0);
                    acc[i][j] = __builtin_amdgcn_mfma_f32_16x16x32_bf16(al[i], bh[j], acc[i][j], 0, 0, 0);
                }
        }
        __syncthreads();
    }
    const int mr0 = (w >> 1) * 64, nc0 = (w & 1) * 64;
#pragma unroll
    for (int j = 0; j < 4; ++j) {
        const int col = nb * 128 + nc0 + j * 16 + (l & 15);
        const float bv = bias[col];
#pragma unroll
        for (int i = 0; i < 4; ++i) {
            const int row0 = mb * 128 + mr0 + i * 16 + (l >> 4) * 4;
#pragma unroll
            for (int rg = 0; rg < 4; ++rg)
                C[(size_t)(row0 + rg) * 1536 + col] = acc[i][j][rg] + bv;
        }
    }
}

// ---- Phase 2: one GRU step, split-bf16 MFMA. 512 blocks x 64 thr. ----
// bid = rt*32 + ct: the 16 rt-blocks sharing a w_hh column-slice are
// stride-32 apart (bid%8 const) -> same XCD -> slice stays L2-resident.
// h carried ONLY as fp32 ping-pong; split in-register while staging.
__global__ __launch_bounds__(64) void gru_step_mfma(
    const float* __restrict__ gi_s,  // [256,1536]
    const float* __restrict__ whh,   // fp32 [1536,512]
    const float* __restrict__ bhh,   // [1536]
    const float* __restrict__ hold,  // fp32 [256,512]  h(t-1)
    float* __restrict__ hnew)        // fp32 [256,512]  h(t)
{
    __shared__ __attribute__((aligned(16))) unsigned char lds[16384];
    // A_hi[0,2K) A_lo[2K,4K) B_hi[4K,10K) B_lo[10K,16K)
    const int l = threadIdx.x;
    const int bid = blockIdx.x;
    const int ct = bid & 31;        // col tile -> c0..c0+15
    const int rt = bid >> 5;        // row tile -> row0..row0+15
    const int c0 = ct * 16, row0 = rt * 16;
    const int p = l & 7, rb = l >> 3;
    f32x4 acc[3] = {};

    for (int kk = 0; kk < 512; kk += 64) {
#pragma unroll
        for (int i = 0; i < 2; ++i) {          // A: h rows, 16x64
            const int r = i * 8 + rb;
            const int q = p ^ (r & 7);
            const float* g = hold + (size_t)(row0 + r) * 512 + kk + q * 8;
            SV h, lo;
            split8(*(const float4*)g, *(const float4*)(g + 4), h, lo);
            const int o = r * 128 + p * 16;
            *(short8v*)&lds[o] = h.v;
            *(short8v*)&lds[2048 + o] = lo.v;
        }
#pragma unroll
        for (int i = 0; i < 6; ++i) {          // B: 3 gates x 16 cols, 48x64
            const int r = i * 8 + rb;          // 0..47
            const int q = p ^ (r & 7);
            const int wrow = ((r >> 4) << 9) + c0 + (r & 15);
            const float* g = whh + (size_t)wrow * 512 + kk + q * 8;
            SV h, lo;
            split8(*(const float4*)g, *(const float4*)(g + 4), h, lo);
            const int o = r * 128 + p * 16;
            *(short8v*)&lds[4096 + o] = h.v;
            *(short8v*)&lds[10240 + o] = lo.v;
        }
        __syncthreads();
#pragma unroll
        for (int kk2 = 0; kk2 < 2; ++kk2) {
            const int kap = kk2 * 4 + (l >> 4);
            const int arow = l & 15;
            const int aoff = arow * 128 + ((kap ^ (arow & 7)) * 16);
            const short8v ah = *(const short8v*)&lds[aoff];
            const short8v al = *(const short8v*)&lds[2048 + aoff];
#pragma unroll
            for (int j = 0; j < 3; ++j) {
                const int bn = j * 16 + (l & 15);
                const int boff = bn * 128 + ((kap ^ (bn & 7)) * 16);
                const short8v bh = *(const short8v*)&lds[4096 + boff];
                const short8v bl = *(const short8v*)&lds[10240 + boff];
                acc[j] = __builtin_amdgcn_mfma_f32_16x16x32_bf16(ah, bh, acc[j], 0, 0, 0);
                acc[j] = __builtin_amdgcn_mfma_f32_16x16x32_bf16(ah, bl, acc[j], 0, 0, 0);
                acc[j] = __builtin_amdgcn_mfma_f32_16x16x32_bf16(al, bh, acc[j], 0, 0, 0);
            }
        }
        __syncthreads();
    }
    const int col = c0 + (l & 15);
    const float br = bhh[col], bz = bhh[512 + col], bnn = bhh[1024 + col];
#pragma unroll
    for (int rg = 0; rg < 4; ++rg) {
        const int row = row0 + (l >> 4) * 4 + rg;
        const float* gp = gi_s + (size_t)row * 1536 + col;
        const float hv = hold[(size_t)row * 512 + col];
        const float r = sigmoidf_(gp[0]    + acc[0][rg] + br);
        const float z = sigmoidf_(gp[512]  + acc[1][rg] + bz);
        const float n = tanhf(gp[1024] + r * (acc[2][rg] + bnn));
        hnew[(size_t)row * 512 + col] = (1.0f - z) * n + z * hv;
    }
}

// ---- Phase 3 fp32 GEMM (exact; known-good) ----
template<bool TANH>
__global__ __launch_bounds__(256) void gemm_nt_bias(
    const float* __restrict__ A, const float* __restrict__ B,
    const float* __restrict__ bias, float* __restrict__ C,
    const int N, const int K)
{
    __shared__ float As[32][68];
    __shared__ float Bs[32][68];
    const int nb = blockIdx.x, mb = blockIdx.y;
    const int t  = threadIdx.x;
    const int tx = t & 15, ty = t >> 4;
    const int lr = t >> 3;
    const int lk = (t & 7) << 2;
    const float* pA = A + (size_t)(mb * 64 + lr) * K + lk;
    const float* pB = B + (size_t)(nb * 64 + lr) * K + lk;
    float acc[4][4];
#pragma unroll
    for (int i = 0; i < 4; ++i)
#pragma unroll
        for (int j = 0; j < 4; ++j) acc[i][j] = 0.0f;
    for (int kk = 0; kk < K; kk += 32) {
        const float4 a0 = *(const float4*)(pA + kk);
        const float4 a1 = *(const float4*)(pA + (size_t)32 * K + kk);
        const float4 b0 = *(const float4*)(pB + kk);
        const float4 b1 = *(const float4*)(pB + (size_t)32 * K + kk);
        __syncthreads();
        As[lk+0][lr] = a0.x; As[lk+1][lr] = a0.y; As[lk+2][lr] = a0.z; As[lk+3][lr] = a0.w;
        As[lk+0][lr+32] = a1.x; As[lk+1][lr+32] = a1.y; As[lk+2][lr+32] = a1.z; As[lk+3][lr+32] = a1.w;
        Bs[lk+0][lr] = b0.x; Bs[lk+1][lr] = b0.y; Bs[lk+2][lr] = b0.z; Bs[lk+3][lr] = b0.w;
        Bs[lk+0][lr+32] = b1.x; Bs[lk+1][lr+32] = b1.y; Bs[lk+2][lr+32] = b1.z; Bs[lk+3][lr+32] = b1.w;
        __syncthreads();
#pragma unroll
        for (int k = 0; k < 32; ++k) {
            const float4 av = *(const float4*)&As[k][ty << 2];
            const float4 bv = *(const float4*)&Bs[k][tx << 2];
            acc[0][0] += av.x * bv.x; acc[0][1] += av.x * bv.y; acc[0][2] += av.x * bv.z; acc[0][3] += av.x * bv.w;
            acc[1][0] += av.y * bv.x; acc[1][1] += av.y * bv.y; acc[1][2] += av.y * bv.z; acc[1][3] += av.y * bv.w;
            acc[2][0] += av.z * bv.x; acc[2][1] += av.z * bv.y; acc[2][2] += av.z * bv.z; acc[2][3] += av.z * bv.w;
            acc[3][0] += av.w * bv.x; acc[3][1] += av.w * bv.y; acc[3][2] += av.w * bv.z; acc[3][3] += av.w * bv.w;
        }
    }
    const int crow = mb * 64 + (ty << 2);
    const int ccol = nb * 64 + (tx << 2);
    const float4 bv = *(const float4*)(bias + ccol);
#pragma unroll
    for (int i = 0; i < 4; ++i) {
        float4 o;
        o.x = acc[i][0] + bv.x; o.y = acc[i][1] + bv.y;
        o.z = acc[i][2] + bv.z; o.w = acc[i][3] + bv.w;
        if (TANH) { o.x = tanhf(o.x); o.y = tanhf(o.y); o.z = tanhf(o.z); o.w = tanhf(o.w); }
        *(float4*)(C + (size_t)(crow + i) * N + ccol) = o;
    }
}

__global__ __launch_bounds__(256) void value_head(
    const float* __restrict__ out1, const float* __restrict__ W2,
    const float* __restrict__ b2, float* __restrict__ out)
{
    const int b = blockIdx.x, t = threadIdx.x;
    float p = out1[(size_t)b * 512 + t] * W2[t]
            + out1[(size_t)b * 512 + 256 + t] * W2[256 + t];
#pragma unroll
    for (int off = 32; off > 0; off >>= 1) p += __shfl_down(p, off, 64);
    __shared__ float ps[4];
    if ((t & 63) == 0) ps[t >> 6] = p;
    __syncthreads();
    if (t == 0) out[b] = tanhf(ps[0] + ps[1] + ps[2] + ps[3] + b2[0]);
}

extern "C" void kernel_launch(void* const* d_in, const int* in_sizes, int n_in,
                              void* d_out, int out_size, void* d_ws, size_t ws_size,
                              hipStream_t stream)
{
    (void)in_sizes; (void)n_in; (void)out_size;
    const float* input = (const float*)d_in[0];   // [256,256,512]
    const float* w_ih  = (const float*)d_in[1];   // [1536,512]
    const float* w_hh  = (const float*)d_in[2];   // [1536,512]
    const float* b_ih  = (const float*)d_in[3];   // [1536]
    const float* b_hh  = (const float*)d_in[4];   // [1536]
    const float* W1    = (const float*)d_in[5];   // [512,512]
    const float* b1    = (const float*)d_in[6];   // [512]
    const float* W2    = (const float*)d_in[7];   // [512]
    const float* b2    = (const float*)d_in[8];   // [1]
    float* out = (float*)d_out;
    float* ws  = (float*)d_ws;

    // ws layout (float slots): hA 131072 | hB 131072 | gi chunk...
    // (no bf16 copies anywhere -> no layout-overlap risk)
    float* hA = ws;
    float* hB = ws + 131072;
    float* gi = ws + 262144;
    float* o1 = gi;                                 // reused after gi dead

    const size_t per_step = 256 * 1536;             // gi floats per timestep
    const size_t base = 262144;
    const size_t avail = (ws_size / 4 > base) ? ws_size / 4 - base : 0;
    int Tc = (int)(avail / per_step);
    if (Tc > 256) Tc = 256;
    if (Tc < 1) Tc = 1;

    hipMemsetAsync(hA, 0, 131072 * sizeof(float), stream);   // h(-1) = 0

    float* hcur = hA; float* hnxt = hB;
    for (int t0 = 0; t0 < 256; t0 += Tc) {
        const int tc = (t0 + Tc <= 256) ? Tc : (256 - t0);
        const int Mc = tc * 256;
        gemm_gi_mfma<<<dim3(12, Mc / 128), 256, 0, stream>>>(
            input + (size_t)t0 * 256 * 512, w_ih, b_ih, gi);
        for (int s = 0; s < tc; ++s) {
            gru_step_mfma<<<dim3(512), 64, 0, stream>>>(
                gi + (size_t)s * per_step, w_hh, b_hh, hcur, hnxt);
            float* tf = hcur; hcur = hnxt; hnxt = tf;
        }
    }

    gemm_nt_bias<true><<<dim3(512 / 64, 256 / 64), 256, 0, stream>>>(
        hcur, W1, b1, o1, 512, 512);
    value_head<<<256, 256, 0, stream>>>(o1, W2, b2, out);
}